// Round 5
// baseline (279.102 us; speedup 1.0000x reference)
//
#include <hip/hip_runtime.h>
#include <math.h>

#define L 4096
#define D 1024
#define H 16
#define KV 4
#define DH 64
// G = H/KV = 4

typedef __attribute__((ext_vector_type(8))) short bf16x8;
typedef __attribute__((ext_vector_type(4))) float f32x4;
typedef __attribute__((ext_vector_type(16))) float f32x16;
typedef __attribute__((ext_vector_type(2))) unsigned int u32x2;

static __device__ __forceinline__ unsigned short f2bf(float f) {
    unsigned u = __float_as_uint(f);
    u = (u + 0x7FFF + ((u >> 16) & 1)) >> 16;   // RNE
    return (unsigned short)u;
}

static __device__ __forceinline__ bf16x8 mk8(unsigned a, unsigned b, unsigned c, unsigned d) {
    union { unsigned u[4]; bf16x8 v; } x;
    x.u[0] = a; x.u[1] = b; x.u[2] = c; x.u[3] = d;
    return x.v;
}

#define EXP2F(x) __builtin_amdgcn_exp2f(x)
#define ZERO16 ((f32x16){0.f,0.f,0.f,0.f,0.f,0.f,0.f,0.f,0.f,0.f,0.f,0.f,0.f,0.f,0.f,0.f})

// async global->LDS, 16B per lane; dst must be wave-uniform base (HW: base + lane*16)
#define GLD16(src, dst) \
    __builtin_amdgcn_global_load_lds((__attribute__((address_space(1))) void*)(src), \
                                     (__attribute__((address_space(3))) void*)(dst), 16, 0, 0)

// ---------------------------------------------------------------------------
// prep: x fp32->bf16, and the four weight transposes (dst[n][k] bf16, K=1024).
// ---------------------------------------------------------------------------
__global__ __launch_bounds__(256) void prep_kernel(
        const float* __restrict__ x,  const float* __restrict__ Wq,
        const float* __restrict__ Wk, const float* __restrict__ Wv,
        const float* __restrict__ Wo,
        unsigned short* __restrict__ xb, unsigned short* __restrict__ WqkvT,
        unsigned short* __restrict__ WoT) {
    const int b = blockIdx.x, tid = threadIdx.x;
    if (b < 4096) {
        int i = (b * 256 + tid) * 4;
        float4 v = *(const float4*)&x[i];
        ushort4 o;
        o.x = f2bf(v.x); o.y = f2bf(v.y); o.z = f2bf(v.z); o.w = f2bf(v.w);
        *(ushort4*)&xb[i] = o;
        return;
    }
    __shared__ float t[32][33];
    const float* src; unsigned short* dst; int N, n0, k0;
    if (b < 5120)      { int tq = b - 4096; src = Wq; dst = WqkvT;                     N = 1024; n0 = (tq & 31) * 32; k0 = (tq >> 5) * 32; }
    else if (b < 5376) { int tq = b - 5120; src = Wk; dst = WqkvT + (size_t)1024*1024; N = 256;  n0 = (tq & 7)  * 32; k0 = (tq >> 3) * 32; }
    else if (b < 5632) { int tq = b - 5376; src = Wv; dst = WqkvT + (size_t)1280*1024; N = 256;  n0 = (tq & 7)  * 32; k0 = (tq >> 3) * 32; }
    else               { int tq = b - 5632; src = Wo; dst = WoT;                       N = 1024; n0 = (tq & 31) * 32; k0 = (tq >> 5) * 32; }
    const int tx = tid & 31, ty = tid >> 5;
    #pragma unroll
    for (int j = 0; j < 4; ++j)
        t[ty + 8 * j][tx] = src[(size_t)(k0 + ty + 8 * j) * N + n0 + tx];
    __syncthreads();
    #pragma unroll
    for (int j = 0; j < 4; ++j)
        dst[(size_t)(n0 + ty + 8 * j) * 1024 + k0 + tx] = f2bf(t[tx][ty + 8 * j]);
}

// ---------------------------------------------------------------------------
// bf16 MFMA GEMM (fp32 out) for the Wo projection.
// ---------------------------------------------------------------------------
__global__ __launch_bounds__(256) void gemm_bf16(const unsigned short* __restrict__ A,
                                                 const unsigned short* __restrict__ BT,
                                                 float* __restrict__ C,
                                                 int M, int N, int K) {
    __shared__ unsigned short As[128 * 32];
    __shared__ unsigned short Bs[128 * 32];

    const int tid  = threadIdx.x;
    const int w    = tid >> 6;
    const int lane = tid & 63;
    const int c    = lane & 15;
    const int quad = lane >> 4;
    const int wy = w >> 1, wx = w & 1;
    const int row0 = blockIdx.y * 128;
    const int col0 = blockIdx.x * 128;

    const int ld_row = w * 16 + (lane >> 2);
    const int ld_col = (lane & 3) * 8;

    f32x4 acc[4][4];
    #pragma unroll
    for (int mt = 0; mt < 4; ++mt)
        #pragma unroll
        for (int nt = 0; nt < 4; ++nt)
            acc[mt][nt] = (f32x4){0.f, 0.f, 0.f, 0.f};

    for (int k0 = 0; k0 < K; k0 += 32) {
        __syncthreads();
        GLD16(&A [(size_t)(row0 + ld_row)      * K + k0 + ld_col], &As[w * 512]);
        GLD16(&A [(size_t)(row0 + ld_row + 64) * K + k0 + ld_col], &As[w * 512 + 2048]);
        GLD16(&BT[(size_t)(col0 + ld_row)      * K + k0 + ld_col], &Bs[w * 512]);
        GLD16(&BT[(size_t)(col0 + ld_row + 64) * K + k0 + ld_col], &Bs[w * 512 + 2048]);
        __syncthreads();

        bf16x8 af[4], bfr[4];
        #pragma unroll
        for (int mt = 0; mt < 4; ++mt)
            af[mt] = *(const bf16x8*)&As[(wy * 64 + mt * 16 + c) * 32 + quad * 8];
        #pragma unroll
        for (int nt = 0; nt < 4; ++nt)
            bfr[nt] = *(const bf16x8*)&Bs[(wx * 64 + nt * 16 + c) * 32 + quad * 8];

        #pragma unroll
        for (int mt = 0; mt < 4; ++mt)
            #pragma unroll
            for (int nt = 0; nt < 4; ++nt)
                acc[mt][nt] = __builtin_amdgcn_mfma_f32_16x16x32_bf16(af[mt], bfr[nt], acc[mt][nt], 0, 0, 0);
    }

    #pragma unroll
    for (int mt = 0; mt < 4; ++mt)
        #pragma unroll
        for (int nt = 0; nt < 4; ++nt)
            #pragma unroll
            for (int r = 0; r < 4; ++r)
                C[(size_t)(row0 + wy * 64 + mt * 16 + quad * 4 + r) * N
                  + col0 + wx * 64 + nt * 16 + c] = acc[mt][nt][r];
}

// ---------------------------------------------------------------------------
// Fused QKV GEMM + RoPE epilogue. V is written TRANSPOSED (vbT[kv*DH+d][l])
// so attention can stage V^T rows (L-contiguous) straight into LDS.
// ---------------------------------------------------------------------------
__global__ __launch_bounds__(256) void gemm_qkv_rope(
        const unsigned short* __restrict__ A,
        const unsigned short* __restrict__ BT,
        unsigned short* __restrict__ qb,
        unsigned short* __restrict__ kbuf,
        unsigned short* __restrict__ vbT) {
    __shared__ unsigned short As[128 * 32];
    __shared__ unsigned short Bs[128 * 32];

    const int tid  = threadIdx.x;
    const int w    = tid >> 6;
    const int lane = tid & 63;
    const int c    = lane & 15;
    const int quad = lane >> 4;
    const int wy = w >> 1, wx = w & 1;
    const int row0 = blockIdx.y * 128;
    const int col0 = blockIdx.x * 128;

    const int ld_row = w * 16 + (lane >> 2);
    const int ld_col = (lane & 3) * 8;

    f32x4 acc[4][4];
    #pragma unroll
    for (int mt = 0; mt < 4; ++mt)
        #pragma unroll
        for (int nt = 0; nt < 4; ++nt)
            acc[mt][nt] = (f32x4){0.f, 0.f, 0.f, 0.f};

    for (int k0 = 0; k0 < 1024; k0 += 32) {
        __syncthreads();
        GLD16(&A [(size_t)(row0 + ld_row)      * 1024 + k0 + ld_col], &As[w * 512]);
        GLD16(&A [(size_t)(row0 + ld_row + 64) * 1024 + k0 + ld_col], &As[w * 512 + 2048]);
        GLD16(&BT[(size_t)(col0 + ld_row)      * 1024 + k0 + ld_col], &Bs[w * 512]);
        GLD16(&BT[(size_t)(col0 + ld_row + 64) * 1024 + k0 + ld_col], &Bs[w * 512 + 2048]);
        __syncthreads();

        bf16x8 af[4], bfr[4];
        #pragma unroll
        for (int mt = 0; mt < 4; ++mt)
            af[mt] = *(const bf16x8*)&As[(wy * 64 + mt * 16 + c) * 32 + quad * 8];
        #pragma unroll
        for (int nt = 0; nt < 4; ++nt)
            bfr[nt] = *(const bf16x8*)&Bs[(wx * 64 + nt * 16 + c) * 32 + quad * 8];

        #pragma unroll
        for (int mt = 0; mt < 4; ++mt)
            #pragma unroll
            for (int nt = 0; nt < 4; ++nt)
                acc[mt][nt] = __builtin_amdgcn_mfma_f32_16x16x32_bf16(af[mt], bfr[nt], acc[mt][nt], 0, 0, 0);
    }

    const int colb = col0 + wx * 64;
    if (colb < 1280) {
        unsigned short* dst; int hh, hstride; float scale;
        if (colb < 1024) { dst = qb;   hh = colb >> 6;          hstride = H;  scale = 0.18033688011112042f; }
        else             { dst = kbuf; hh = (colb - 1024) >> 6; hstride = KV; scale = 1.0f; }
        #pragma unroll
        for (int nt = 0; nt < 2; ++nt) {
            int d = nt * 16 + c;
            float invf = EXP2F((float)d * -0.4152410118609203f);
            #pragma unroll
            for (int mt = 0; mt < 4; ++mt)
                #pragma unroll
                for (int r = 0; r < 4; ++r) {
                    int l = row0 + wy * 64 + mt * 16 + quad * 4 + r;
                    float ang = (float)l * invf;
                    float sn = __sinf(ang), cs = __cosf(ang);
                    float x1 = acc[mt][nt][r], x2 = acc[mt][nt + 2][r];
                    dst[((size_t)l * hstride + hh) * DH + d]      = f2bf((x1 * cs - x2 * sn) * scale);
                    dst[((size_t)l * hstride + hh) * DH + d + 32] = f2bf((x2 * cs + x1 * sn) * scale);
                }
        }
    } else {
        // V^T: vbT[(vh*DH + d) * L + l], packed 4 contiguous l per store
        int vh = (colb - 1280) >> 6;
        #pragma unroll
        for (int nt = 0; nt < 4; ++nt)
            #pragma unroll
            for (int mt = 0; mt < 4; ++mt) {
                int l = row0 + wy * 64 + mt * 16 + quad * 4;
                ushort4 o;
                o.x = f2bf(acc[mt][nt][0]); o.y = f2bf(acc[mt][nt][1]);
                o.z = f2bf(acc[mt][nt][2]); o.w = f2bf(acc[mt][nt][3]);
                *(ushort4*)&vbT[(size_t)(vh * DH + nt * 16 + c) * L + l] = o;
            }
    }
}

// ---------------------------------------------------------------------------
// MFMA attention, 32x32x16. Grid (L/32, KV) = (128,4) = 512 blocks -> TWO
// independent blocks per CU (16 waves/CU, 4/SIMD) so one block's barrier
// drain / softmax VALU overlaps the other's MFMA (R3/R4 lesson: 1 block/CU
// was the occupancy cap; VGPR 116 <= 128 allows 16 waves/CU).
// Block: 8 waves = 4 heads x 2 key-groups; wave owns 32 q-rows, 2048 keys
// (32 iters of 64). Per iter: 8 St + 8 PV MFMA (32x32x16).
// V: staged per-group from vbT (V^T, L-contiguous rows) via global_load_lds
// with PRE-SWIZZLED per-lane source (LDS dest linear, source chunk XOR'd by
// row d) -> coalesced 128B-row reads, conflict-reduced ds_reads, no VGPR
// round-trip, no VALU transpose (fixes R4's 32-line scattered V gathers).
// Double-buffered, 1 barrier/iter.
// Softmax fully in-register (exp2 -> bf16-truncate -> perm pack ->
// permlane32_swap); rowsums are VALU adds on truncated values.
// Epilogue: fp32 partial combine in LDS OVERLAYING the dead Vt buffer
// (keeps LDS at 33 KB -> 2 blocks/CU).
// NOTE (R2): plain loop body only — no [&] lambda (scratch catastrophe).
// ---------------------------------------------------------------------------
__global__ __attribute__((amdgpu_flat_work_group_size(512, 512), amdgpu_waves_per_eu(4)))
void attn_mfma_kernel(
        const unsigned short* __restrict__ qb,
        const unsigned short* __restrict__ kb,
        const unsigned short* __restrict__ vbT,
        unsigned short* __restrict__ ob) {
    __shared__ __align__(16) unsigned short Vt[2][2][64][64];  // 32 KB [group][buf][d][key]; epilogue overlay
    __shared__ __align__(16) float Rs[8][32];                  //  1 KB rowsums [wave][q]

    const int tid  = threadIdx.x;
    const int w    = tid >> 6;        // 0..7
    const int lane = tid & 63;
    const int c32  = lane & 31;
    const int hi   = lane >> 5;
    const int g    = w >> 2;          // key group
    const int kv = blockIdx.y;
    const int h  = kv * 4 + (w & 3);
    const int q0 = blockIdx.x * 32;
    const int s_base = g * 2048;

    // ---- V staging source (pre-swizzled): wave stages rows vrow0..vrow0+15
    // of its group's [64 d][64 key] tile; GLD16 slab m covers rows +8m.
    // LDS[d][chunk c] (chunks of 8 keys) holds global chunk c ^ (d&7).
    const int vrow0 = (w & 3) * 16;
    const int d0 = vrow0 + (lane >> 3);                  // slab m adds +8m
    const unsigned short* vsrc0 = vbT + (size_t)(kv * DH + d0) * L + s_base
                                  + (((lane & 7) ^ (d0 & 7)) << 3);
    const unsigned short* vsrc1 = vbT + (size_t)(kv * DH + d0 + 8) * L + s_base
                                  + (((lane & 7) ^ ((d0 + 8) & 7)) << 3);

    // Q B-frags: col=q=c32, k-elems d = kd*16 + hi*8 + j
    bf16x8 qf[4];
    {
        const unsigned short* qbase = qb + ((size_t)(q0 + c32) * H + h) * DH + hi * 8;
        #pragma unroll
        for (int kd = 0; kd < 4; ++kd)
            qf[kd] = *(const bf16x8*)&qbase[kd * 16];
    }

    f32x16 oacc[2];       // [dt]: col=d=dt*32+c32, row=q=(r&3)+8(r>>2)+4hi
    oacc[0] = ZERO16; oacc[1] = ZERO16;
    float rsum = 0.f;     // per-lane partial rowsum, q = c32

    const unsigned short* kbase = kb + ((size_t)(s_base + c32) * KV + kv) * DH + hi * 8;

    // ---- prefetch K iter 0; stage V iter 0 into buf 0 ----
    bf16x8 kf[2][4];   // [key-32-tile][kd]
    #pragma unroll
    for (int a = 0; a < 2; ++a)
        #pragma unroll
        for (int kd = 0; kd < 4; ++kd)
            kf[a][kd] = *(const bf16x8*)&kbase[a * 32 * KV * DH + kd * 16];
    GLD16(vsrc0, &Vt[g][0][vrow0][0]);
    GLD16(vsrc1, &Vt[g][0][vrow0 + 8][0]);

    for (int it = 0; it < 32; ++it) {
        const int buf = it & 1;
        __syncthreads();   // vmcnt(0) drain: V stage (+K prefetch) complete; prior reads of buf^1 done

        if (it != 31) {    // stage next tile into the other buffer (async, overlaps compute)
            GLD16(vsrc0 + (it + 1) * 64, &Vt[g][buf ^ 1][vrow0][0]);
            GLD16(vsrc1 + (it + 1) * 64, &Vt[g][buf ^ 1][vrow0 + 8][0]);
        }
        const int itn = (it + 1) & 31;

        #pragma unroll
        for (int kt2 = 0; kt2 < 2; ++kt2) {
            // St = K @ Q^T (32x32, K-dim = DH via 4 chained MFMAs)
            f32x16 s = ZERO16;
            #pragma unroll
            for (int kd = 0; kd < 4; ++kd)
                s = __builtin_amdgcn_mfma_f32_32x32x16_bf16(kf[kt2][kd], qf[kd], s, 0, 0, 0);

            // exp2 -> bf16-truncate -> rowsum -> pack (two halves bound transients)
            unsigned u[8];
            #pragma unroll
            for (int hf = 0; hf < 2; ++hf) {
                float ph[8];
                #pragma unroll
                for (int r = 0; r < 8; ++r)
                    ph[r] = __uint_as_float(__float_as_uint(EXP2F(s[hf * 8 + r])) & 0xFFFF0000u);
                float t0 = (ph[0] + ph[1]) + (ph[2] + ph[3]);
                float t1 = (ph[4] + ph[5]) + (ph[6] + ph[7]);
                rsum += t0 + t1;
                #pragma unroll
                for (int i = 0; i < 4; ++i)
                    u[hf * 4 + i] = __builtin_amdgcn_perm(__float_as_uint(ph[2 * i + 1]),
                                                          __float_as_uint(ph[2 * i]), 0x07060302u);
            }
            // cross-half redistribute: swap(u0,u2)->slots{0,2}, swap(u1,u3)->slots{1,3}
            bf16x8 pf[2];
            #pragma unroll
            for (int f = 0; f < 2; ++f) {
                u32x2 e0 = __builtin_amdgcn_permlane32_swap(u[4 * f + 0], u[4 * f + 2], false, false);
                u32x2 e1 = __builtin_amdgcn_permlane32_swap(u[4 * f + 1], u[4 * f + 3], false, false);
                pf[f] = mk8(e0.x, e1.x, e0.y, e1.y);
            }
            if (kt2 == 1) {
                // K prefetch next iter (after last St read of kf)
                #pragma unroll
                for (int a = 0; a < 2; ++a)
                    #pragma unroll
                    for (int kd = 0; kd < 4; ++kd)
                        kf[a][kd] = *(const bf16x8*)&kbase[((size_t)itn * 64 + a * 32) * KV * DH + kd * 16];
            }
            // ---- PV half-tile: O += P @ V over keys kt2*32..+31 ----
            __builtin_amdgcn_s_setprio(1);
            #pragma unroll
            for (int dt = 0; dt < 2; ++dt)
                #pragma unroll
                for (int f = 0; f < 2; ++f) {
                    // phys chunk = logical (kt2*4+f*2+hi) XOR (d&7), d = dt*32+c32
                    bf16x8 vf = *(const bf16x8*)&Vt[g][buf][dt * 32 + c32]
                                    [(((kt2 * 4 + f * 2 + hi) ^ (c32 & 7)) << 3)];
                    oacc[dt] = __builtin_amdgcn_mfma_f32_32x32x16_bf16(pf[f], vf, oacc[dt], 0, 0, 0);
                }
            __builtin_amdgcn_s_setprio(0);
        }
    }

    // ---- epilogue: combine hi-halves of rowsums, then key-groups ----
    float tot;
    {
        u32x2 e = __builtin_amdgcn_permlane32_swap(__float_as_uint(rsum),
                                                   __float_as_uint(rsum), false, false);
        tot = __uint_as_float(e.x) + __uint_as_float(e.y);
    }
    __syncthreads();   // all PV reads of Vt complete -> safe to overlay
    float (*Ep)[64][32] = (float (*)[64][32])(&Vt[0][0][0][0]);   // 4 x 8 KB fp32 partials
    Rs[w][c32] = tot;  // both hi-lanes write same value (benign)
    if (g == 1) {
        #pragma unroll
        for (int dt = 0; dt < 2; ++dt) {
            const int d = dt * 32 + c32;
            #pragma unroll
            for (int rr = 0; rr < 4; ++rr) {
                const int gq = (2 * rr + hi) ^ (d & 7);   // 16B-granule swizzle
                f32x4 val = {oacc[dt][rr * 4 + 0], oacc[dt][rr * 4 + 1],
                             oacc[dt][rr * 4 + 2], oacc[dt][rr * 4 + 3]};
                *(f32x4*)&Ep[w - 4][d][gq * 4] = val;
            }
        }
    }
    __syncthreads();
    if (g == 0) {
        #pragma unroll
        for (int dt = 0; dt < 2; ++dt) {
            const int d = dt * 32 + c32;
            #pragma unroll
            for (int rr = 0; rr < 4; ++rr) {
                const int gq = (2 * rr + hi) ^ (d & 7);
                f32x4 val = *(const f32x4*)&Ep[w][d][gq * 4];
                oacc[dt][rr * 4 + 0] += val[0];
                oacc[dt][rr * 4 + 1] += val[1];
                oacc[dt][rr * 4 + 2] += val[2];
                oacc[dt][rr * 4 + 3] += val[3];
            }
        }
        #pragma unroll
        for (int rr = 0; rr < 4; ++rr) {
            f32x4 ra = *(const f32x4*)&Rs[w][8 * rr + 4 * hi];
            f32x4 rb = *(const f32x4*)&Rs[w + 4][8 * rr + 4 * hi];
            #pragma unroll
            for (int i = 0; i < 4; ++i) {
                float inv = 1.0f / (ra[i] + rb[i]);
                int row = q0 + 8 * rr + 4 * hi + i;
                #pragma unroll
                for (int dt = 0; dt < 2; ++dt)
                    ob[(size_t)row * (H * DH) + h * DH + dt * 32 + c32] =
                        f2bf(oacc[dt][rr * 4 + i] * inv);
            }
        }
    }
}

// ---------------------------------------------------------------------------
extern "C" void kernel_launch(void* const* d_in, const int* in_sizes, int n_in,
                              void* d_out, int out_size, void* d_ws, size_t ws_size,
                              hipStream_t stream) {
    const float* x  = (const float*)d_in[0];
    const float* Wq = (const float*)d_in[1];
    const float* Wk = (const float*)d_in[2];
    const float* Wv = (const float*)d_in[3];
    const float* Wo = (const float*)d_in[4];
    float* out = (float*)d_out;

    // ---- workspace (~26.2 MB) ----
    char* ws = (char*)d_ws;
    unsigned short* xb    = (unsigned short*)ws;                      // 8.39 MB
    unsigned short* ob    = xb;                                       // aliases xb (dead after QKV GEMM)
    unsigned short* qb    = (unsigned short*)(ws + 8388608);          // 8.39 MB
    unsigned short* kb    = (unsigned short*)(ws + 16777216);         // 2.10 MB
    unsigned short* vbT   = (unsigned short*)(ws + 18874368);         // 2.10 MB (V transposed [kv*DH+d][L])
    unsigned short* WqkvT = (unsigned short*)(ws + 20971520);         // 3.15 MB
    unsigned short* WoT   = (unsigned short*)(ws + 24117248);         // 2.10 MB

    dim3 blk(256);

    // 1) convert + transpose everything
    prep_kernel<<<6656, blk, 0, stream>>>(x, Wq, Wk, Wv, Wo, xb, WqkvT, WoT);

    // 2) fused QKV projection + RoPE + bf16 pack (V written transposed)
    gemm_qkv_rope<<<dim3(12, 32), blk, 0, stream>>>(xb, WqkvT, qb, kb, vbT);

    // 3) attention: 512 blocks of 8 waves -> 2 blocks/CU
    attn_mfma_kernel<<<dim3(L / 32, KV), dim3(512), 0, stream>>>(qb, kb, vbT, ob);

    // 4) output projection
    gemm_bf16<<<dim3(D / 128, L / 128), blk, 0, stream>>>(ob, WoT, out, L, D, D);
}